// Round 1
// baseline (732.898 us; speedup 1.0000x reference)
//
#include <hip/hip_runtime.h>

typedef unsigned int uint32;
typedef unsigned long long u64;

#define NBATCH 8
#define NPTS   4096
#define KNN    16
#define NBASIS 8
#define OUTM   64
#define CAP    32
#define TKNN   128
#define NCHUNK 2
#define CHUNK  (NPTS / NCHUNK)   /* 2048 */
#define TFEAT  64

__device__ __forceinline__ void ce(u64& x, u64& y) {
  u64 a = x, b = y;
  bool sw = b < a;
  x = sw ? b : a;
  y = sw ? a : b;
}

// Batcher odd-even mergesort, fully static -> compiler unrolls to a network.
template <int N>
__device__ __forceinline__ void oems_sort(u64* a) {
#pragma unroll
  for (int p = 1; p < N; p <<= 1) {
#pragma unroll
    for (int k = p; k >= 1; k >>= 1) {
#pragma unroll
      for (int j = k & (p - 1); j + k < N; j += 2 * k) {
#pragma unroll
        for (int i = 0; i < k; ++i) {
          int lo = i + j, hi = i + j + k;
          if (hi < N && (lo / (2 * p)) == (hi / (2 * p)))
            ce(a[lo], a[hi]);
        }
      }
    }
  }
}

// Compact a thread's LDS candidate buffer to its exact top-16 (sorted),
// tighten threshold to the 16th-smallest d2. noinline: keep out of the
// unrolled hot loop (called rarely, wave-uniformly).
__device__ __attribute__((noinline)) void compact_buf(u64 (*sB)[TKNN], int tid,
                                                      int& c, float& thr) {
  u64 arr[CAP];
#pragma unroll
  for (int e = 0; e < CAP; ++e) {
    u64 v = sB[e][tid];
    arr[e] = (e < c) ? v : ~0ull;
  }
  oems_sort<CAP>(arr);
#pragma unroll
  for (int e = 0; e < KNN; ++e) sB[e][tid] = arr[e];
  if (c >= KNN) {
    c = KNN;
    thr = __uint_as_float((uint32)(arr[KNN - 1] >> 32));
  }
}

// Per (batch, query-group, candidate-chunk): exact top-16 of chunk, sorted,
// written as packed u64 (d2_bits<<32 | idx) to ws.
__global__ __launch_bounds__(TKNN) void knn_kernel(const float4* __restrict__ cpad,
                                                   u64* __restrict__ part) {
  __shared__ float4 sC[CHUNK];     // 32 KB candidate stage
  __shared__ u64 sB[CAP][TKNN];    // 32 KB per-thread buffers (column per thread)
  const int b = blockIdx.x;
  const int qg = blockIdx.y;
  const int ch = blockIdx.z;
  const int tid = threadIdx.x;
  const int qi = qg * TKNN + tid;
  const float4* cb = cpad + b * NPTS;
  const int jbase = ch * CHUNK;

  for (int p = tid; p < CHUNK; p += TKNN) sC[p] = cb[jbase + p];
  __syncthreads();

  const float4 q = cb[qi];
  const float qx = q.x, qy = q.y, qz = q.z;

  int c = 0;
  float thr = __int_as_float(0x7f800000);  // +inf

#pragma unroll 8
  for (int jj = 0; jj < CHUNK; ++jj) {
    float4 bp = sC[jj];              // wave-uniform address -> LDS broadcast
    int j = jbase + jj;
    // Bit-exact match of reference: (a-b) squared, summed ((x+y)+z), no FMA.
    float dx = __fadd_rn(qx, -bp.x);
    float dy = __fadd_rn(qy, -bp.y);
    float dz = __fadd_rn(qz, -bp.z);
    float d2 = __fadd_rn(__fadd_rn(__fmul_rn(dx, dx), __fmul_rn(dy, dy)),
                         __fmul_rn(dz, dz));
    bool want = (d2 <= thr) && (j != qi);
    if (__any(want)) {
      if (__any(c == CAP)) compact_buf(sB, tid, c, thr);
      if (want) {
        sB[c][tid] = ((u64)__float_as_uint(d2) << 32) | (uint32)j;
        c++;
      }
    }
  }

  // Final: sorted exact top-16 of this chunk -> ws.
  compact_buf(sB, tid, c, thr);
  u64* op = part + ((size_t)(b * NPTS + qi) * NCHUNK + ch) * KNN;
#pragma unroll
  for (int e = 0; e < KNN; ++e) op[e] = sB[e][tid];
}

// Merge the NCHUNK sorted 16-lists per query, then compute edge features,
// aggregate M[8][3], apply W (8x64) and write out[q][w*3+m].
__global__ __launch_bounds__(TFEAT) void feat_kernel(const float4* __restrict__ cpad,
                                                     const u64* __restrict__ part,
                                                     const float* __restrict__ Wmat,
                                                     float* __restrict__ out) {
  __shared__ u64 sP[TFEAT * 33];        // 32 entries/query, +1 u64 pad
  __shared__ float sW[OUTM * NBASIS];   // transposed: [w][v]
  const int tid = threadIdx.x;
  const int qblock = blockIdx.x * TFEAT;

  for (int i = tid; i < OUTM * NBASIS; i += TFEAT) {
    int v = i >> 6, w = i & 63;          // input layout [v][w]
    sW[w * NBASIS + v] = Wmat[i];
  }
  const size_t pbase = (size_t)qblock * (NCHUNK * KNN);
  for (int i = tid; i < TFEAT * NCHUNK * KNN; i += TFEAT) {
    int ql = i >> 5, e = i & 31;
    sP[ql * 33 + e] = part[pbase + i];
  }
  __syncthreads();

  const int q = qblock + tid;
  const int b = q >> 12;                 // /4096
  const int qi = q & (NPTS - 1);
  const float4* cb = cpad + b * NPTS;
  const float4 qc = cb[qi];

  // 2-way merge of two sorted 16-lists (u64 lex order = (d2, idx)).
  int idxs[KNN];
  float d2s[KNN];
  {
    int ia = 0, ibx = 0;
    const u64* lp = sP + tid * 33;
#pragma unroll
    for (int r = 0; r < KNN; ++r) {
      u64 va = lp[ia];
      u64 vb = lp[16 + ibx];
      bool ta = va <= vb;
      u64 v = ta ? va : vb;
      ia += ta ? 1 : 0;
      ibx += ta ? 0 : 1;
      idxs[r] = (int)(uint32)v;
      d2s[r] = __uint_as_float((uint32)(v >> 32));
    }
  }

  float4 nc[KNN];
#pragma unroll
  for (int r = 0; r < KNN; ++r) nc[r] = cb[idxs[r]];  // independent gathers

  float M[NBASIS][3];
#pragma unroll
  for (int v = 0; v < NBASIS; ++v) M[v][0] = M[v][1] = M[v][2] = 0.f;

#pragma unroll
  for (int r = 0; r < KNN; ++r) {
    float rx = nc[r].x - qc.x;           // sender - receiver
    float ry = nc[r].y - qc.y;
    float rz = nc[r].z - qc.z;
    float dist = sqrtf(d2s[r]);
    float inv = 1.0f / (dist + 1e-8f);
    rx *= inv; ry *= inv; rz *= inv;
    float cut = fminf(dist * 0.1f, 1.0f);
    float g[NBASIS], s = 0.f;
#pragma unroll
    for (int v = 0; v < NBASIS; ++v) {
      float t = cut - (float)v * (1.0f / 7.0f);
      g[v] = __expf(-32.0f * t * t);     // sigma = 1/8 -> 1/(2s^2) = 32
      s += g[v];
    }
    float rs = 1.0f / s;
#pragma unroll
    for (int v = 0; v < NBASIS; ++v) {
      float rb = g[v] * rs;
      M[v][0] = fmaf(rb, rx, M[v][0]);
      M[v][1] = fmaf(rb, ry, M[v][1]);
      M[v][2] = fmaf(rb, rz, M[v][2]);
    }
  }

  const float scale = 0.022097086912079608f;  // (1/sqrt(8)) / 16
  float* op = out + (size_t)q * (OUTM * 3);
  for (int w = 0; w < OUTM; ++w) {
    const float* wv = sW + w * NBASIS;
    float a0 = 0.f, a1 = 0.f, a2 = 0.f;
#pragma unroll
    for (int v = 0; v < NBASIS; ++v) {
      float wc = wv[v];
      a0 = fmaf(wc, M[v][0], a0);
      a1 = fmaf(wc, M[v][1], a1);
      a2 = fmaf(wc, M[v][2], a2);
    }
    op[w * 3 + 0] = a0 * scale;
    op[w * 3 + 1] = a1 * scale;
    op[w * 3 + 2] = a2 * scale;
  }
}

// Pad coords [B*N][3] -> float4 [B*N] for aligned 16B loads.
__global__ void prep_kernel(const float* __restrict__ coords,
                            float4* __restrict__ cpad) {
  int i = blockIdx.x * 256 + threadIdx.x;
  if (i < NBATCH * NPTS) {
    float x = coords[3 * i + 0];
    float y = coords[3 * i + 1];
    float z = coords[3 * i + 2];
    cpad[i] = make_float4(x, y, z, 0.f);
  }
}

extern "C" void kernel_launch(void* const* d_in, const int* in_sizes, int n_in,
                              void* d_out, int out_size, void* d_ws, size_t ws_size,
                              hipStream_t stream) {
  const float* coords = (const float*)d_in[0];
  const float* Wmat = (const float*)d_in[1];
  float* out = (float*)d_out;

  float4* cpad = (float4*)d_ws;
  u64* part = (u64*)((char*)d_ws + (size_t)NBATCH * NPTS * sizeof(float4));

  prep_kernel<<<dim3((NBATCH * NPTS + 255) / 256), dim3(256), 0, stream>>>(coords, cpad);
  knn_kernel<<<dim3(NBATCH, NPTS / TKNN, NCHUNK), dim3(TKNN), 0, stream>>>(cpad, part);
  feat_kernel<<<dim3(NBATCH * NPTS / TFEAT), dim3(TFEAT), 0, stream>>>(cpad, part, Wmat, out);
}

// Round 2
// 236.793 us; speedup vs baseline: 3.0951x; 3.0951x over previous
//
#include <hip/hip_runtime.h>

typedef unsigned int u32;
typedef unsigned long long u64;

#define NBATCH 8
#define NPTS   4096
#define KNN    16
#define NBASIS 8
#define OUTM   64
#define NCHUNK 2
#define CHUNK  (NPTS / NCHUNK)    /* 2048 */
#define NSPLIT 2
#define SUBCH  (CHUNK / NSPLIT)   /* 1024 */
#define TKNN   256                /* 128 queries x 2 splits */
#define QPB    128
#define CAP    16                 /* LDS append buffer depth */
#define GRP    8
#define TFEAT  128
#define NQTOT  (NBATCH * NPTS)    /* 32768 */

// sentinel: d2 = +inf, idx = all-ones (sorts last, compares sanely)
#define SENT 0x7f800000ffffffffull

__device__ __forceinline__ void ce(u64& x, u64& y) {
  u64 a = x, b = y;
  bool sw = b < a;
  x = sw ? b : a;
  y = sw ? a : b;
}

// Batcher odd-even mergesort network (fully unrolled).
template <int N>
__device__ __forceinline__ void oems_sort(u64* a) {
#pragma unroll
  for (int p = 1; p < N; p <<= 1) {
#pragma unroll
    for (int k = p; k >= 1; k >>= 1) {
#pragma unroll
      for (int j = k & (p - 1); j + k < N; j += 2 * k) {
#pragma unroll
        for (int i = 0; i < k; ++i) {
          int lo = i + j, hi = i + j + k;
          if (hi < N && (lo / (2 * p)) == (hi / (2 * p)))
            ce(a[lo], a[hi]);
        }
      }
    }
  }
}

// t (sorted asc) , a (sorted asc) -> t = smallest 16 of union, sorted asc.
// Bitonic half-cleaner (16 mins) + bitonic merge network (32 CEs).
__device__ __forceinline__ void merge16(u64 t[16], const u64 a[16]) {
  u64 m[16];
#pragma unroll
  for (int i = 0; i < 16; ++i) {
    u64 x = t[i], y = a[15 - i];
    m[i] = (x < y) ? x : y;
  }
#pragma unroll
  for (int k = 8; k >= 1; k >>= 1) {
#pragma unroll
    for (int i = 0; i < 16; ++i) {
      if ((i & k) == 0) ce(m[i], m[i | k]);
    }
  }
#pragma unroll
  for (int i = 0; i < 16; ++i) t[i] = m[i];
}

// Flush the per-thread LDS append buffer into the register top-16.
__device__ __forceinline__ void flush_buf(u64* col, int& c, u64 t16[16],
                                          float& thr) {
  u64 a[16];
#pragma unroll
  for (int e = 0; e < 16; ++e) {
    u64 v = col[e * TKNN];
    a[e] = (e < c) ? v : SENT;
  }
  oems_sort<16>(a);
  merge16(t16, a);
  c = 0;
  thr = __uint_as_float((u32)(t16[15] >> 32));
}

// Per (batch, 128-query group, chunk): each thread scans SUBCH candidates,
// keeps exact (d2,idx)-lex top-16 in registers; splits merged in-block;
// sorted 16-list written plane-major for coalesced feat reads.
__global__ __launch_bounds__(TKNN) void knn_kernel(const float4* __restrict__ cpad,
                                                   u64* __restrict__ part) {
  __shared__ u64 sB[CAP * TKNN];  // 32 KB append buffer / merge staging
  const int b = blockIdx.x;
  const int qg = blockIdx.y;
  const int ch = blockIdx.z;
  const int tid = threadIdx.x;
  const int ql = tid & (QPB - 1);
  const int sp = tid >> 7;               // split id, wave-uniform
  const int qi = qg * QPB + ql;
  const float4* cb = cpad + b * NPTS;
  const float4 q = cb[qi];
  const int jbase = ch * CHUNK + sp * SUBCH;

  u64 t16[16];
#pragma unroll
  for (int e = 0; e < 16; ++e) t16[e] = SENT;
  int c = 0;
  float thr = __int_as_float(0x7f800000);  // +inf
  u64* col = sB + tid;

  for (int g = 0; g < SUBCH; g += GRP) {
    float4 bp[GRP];
#pragma unroll
    for (int i = 0; i < GRP; ++i) bp[i] = cb[jbase + g + i];  // wave-uniform
    float d2v[GRP];
    int want[GRP];
    int wany = 0;
#pragma unroll
    for (int i = 0; i < GRP; ++i) {
      int j = jbase + g + i;
      // Bit-exact vs reference: separate mul/add, no FMA contraction.
      float dx = __fadd_rn(q.x, -bp[i].x);
      float dy = __fadd_rn(q.y, -bp[i].y);
      float dz = __fadd_rn(q.z, -bp[i].z);
      d2v[i] = __fadd_rn(__fadd_rn(__fmul_rn(dx, dx), __fmul_rn(dy, dy)),
                         __fmul_rn(dz, dz));
      want[i] = (d2v[i] <= thr) && (j != qi);
      wany |= want[i];
    }
    if (__any(wany)) {
      if (__any(c > CAP - GRP)) flush_buf(col, c, t16, thr);
#pragma unroll
      for (int i = 0; i < GRP; ++i) {
        if (want[i]) {
          col[c * TKNN] =
              ((u64)__float_as_uint(d2v[i]) << 32) | (u32)(jbase + g + i);
          c++;
        }
      }
    }
  }
  flush_buf(col, c, t16, thr);

  // Cross-split merge: split 1 publishes, split 0 merges + writes.
  __syncthreads();  // append buffer dead; safe to repurpose
  if (sp == 1) {
#pragma unroll
    for (int e = 0; e < 16; ++e) sB[ql * 17 + e] = t16[e];  // +1 pad: no bank conflict
  }
  __syncthreads();
  if (sp == 0) {
    u64 a[16];
#pragma unroll
    for (int e = 0; e < 16; ++e) a[e] = sB[ql * 17 + e];
    merge16(t16, a);
    u64* pb = part + (size_t)b * NPTS + qi;
#pragma unroll
    for (int e = 0; e < 16; ++e)
      pb[(size_t)(ch * KNN + e) * NQTOT] = t16[e];  // coalesced per plane
  }
}

// Merge per-query chunk lists, compute edge features, aggregate M[8][3],
// apply W with coalesced output via LDS transpose.
__global__ __launch_bounds__(TFEAT) void feat_kernel(const float4* __restrict__ cpad,
                                                     const u64* __restrict__ part,
                                                     const float* __restrict__ Wmat,
                                                     float* __restrict__ out) {
  __shared__ float sM[TFEAT * 28];  // M[8][3] per query, stride 28 (16B aligned)
  const int tid = threadIdx.x;
  const int gq0 = blockIdx.x * TFEAT;
  const int gq = gq0 + tid;
  const int b = gq >> 12;
  const int qi = gq & (NPTS - 1);
  const float4* cb = cpad + b * NPTS;
  const float4 qc = cb[qi];

  // W column for this lane: w = lane id (0..63), 8 coalesced loads.
  const int wlane = tid & 63;
  float wreg[NBASIS];
#pragma unroll
  for (int v = 0; v < NBASIS; ++v) wreg[v] = Wmat[v * OUTM + wlane];

  // Load the two sorted 16-lists (coalesced: lane-consecutive gq per plane).
  u64 A[16], Bv[16];
#pragma unroll
  for (int e = 0; e < 16; ++e) A[e] = part[(size_t)e * NQTOT + gq];
#pragma unroll
  for (int e = 0; e < 16; ++e) Bv[e] = part[(size_t)(KNN + e) * NQTOT + gq];
  merge16(A, Bv);  // A = exact top-16, sorted

  int idxs[KNN];
  float d2s[KNN];
#pragma unroll
  for (int r = 0; r < KNN; ++r) {
    idxs[r] = (int)(u32)A[r];
    d2s[r] = __uint_as_float((u32)(A[r] >> 32));
  }
  float4 nc[KNN];
#pragma unroll
  for (int r = 0; r < KNN; ++r) nc[r] = cb[idxs[r]];  // independent gathers

  float M[NBASIS][3];
#pragma unroll
  for (int v = 0; v < NBASIS; ++v) M[v][0] = M[v][1] = M[v][2] = 0.f;

#pragma unroll
  for (int r = 0; r < KNN; ++r) {
    float rx = nc[r].x - qc.x;  // sender - receiver
    float ry = nc[r].y - qc.y;
    float rz = nc[r].z - qc.z;
    float dist = sqrtf(d2s[r]);
    float inv = 1.0f / (dist + 1e-8f);
    rx *= inv; ry *= inv; rz *= inv;
    float cut = fminf(dist * 0.1f, 1.0f);
    float g[NBASIS], s = 0.f;
#pragma unroll
    for (int v = 0; v < NBASIS; ++v) {
      float t = cut - (float)v * (1.0f / 7.0f);
      g[v] = __expf(-32.0f * t * t);  // sigma = 1/8 -> 1/(2s^2) = 32
      s += g[v];
    }
    float rs = 1.0f / s;
#pragma unroll
    for (int v = 0; v < NBASIS; ++v) {
      float rb = g[v] * rs;
      M[v][0] = fmaf(rb, rx, M[v][0]);
      M[v][1] = fmaf(rb, ry, M[v][1]);
      M[v][2] = fmaf(rb, rz, M[v][2]);
    }
  }

  // Publish M to LDS (6 aligned float4 stores).
  {
    float4* mrow = (float4*)(sM + tid * 28);
#pragma unroll
    for (int j = 0; j < 6; ++j) {
      float4 t;
      t.x = M[0][0]; // placeholder overwritten below via flat mapping
      (void)t;
      float e0 = (&M[0][0])[j * 4 + 0];
      float e1 = (&M[0][0])[j * 4 + 1];
      float e2 = (&M[0][0])[j * 4 + 2];
      float e3 = (&M[0][0])[j * 4 + 3];
      mrow[j] = make_float4(e0, e1, e2, e3);
    }
  }
  __syncthreads();

  // Phase 2: output triple t3 = k*TFEAT + tid -> (q_l = t3>>6, w = t3&63).
  // q_l is wave-uniform per k -> sM reads broadcast; stores near-coalesced.
  const float scale = 0.022097086912079608f;  // (1/sqrt(8)) / 16
  const size_t obase = (size_t)gq0 * (OUTM * 3);
#pragma unroll 2
  for (int k = 0; k < 64; ++k) {
    int t3 = k * TFEAT + tid;
    int q_l = t3 >> 6;
    const float* mq = sM + q_l * 28;
    float Mv[24];
#pragma unroll
    for (int j = 0; j < 6; ++j) {
      float4 f = ((const float4*)mq)[j];
      Mv[j * 4 + 0] = f.x;
      Mv[j * 4 + 1] = f.y;
      Mv[j * 4 + 2] = f.z;
      Mv[j * 4 + 3] = f.w;
    }
    float a0 = 0.f, a1 = 0.f, a2 = 0.f;
#pragma unroll
    for (int v = 0; v < NBASIS; ++v) {
      a0 = fmaf(wreg[v], Mv[v * 3 + 0], a0);
      a1 = fmaf(wreg[v], Mv[v * 3 + 1], a1);
      a2 = fmaf(wreg[v], Mv[v * 3 + 2], a2);
    }
    size_t o = obase + (size_t)t3 * 3;
    out[o + 0] = a0 * scale;
    out[o + 1] = a1 * scale;
    out[o + 2] = a2 * scale;
  }
}

// Pad coords [B*N][3] -> float4 [B*N].
__global__ void prep_kernel(const float* __restrict__ coords,
                            float4* __restrict__ cpad) {
  int i = blockIdx.x * 256 + threadIdx.x;
  if (i < NQTOT) {
    float x = coords[3 * i + 0];
    float y = coords[3 * i + 1];
    float z = coords[3 * i + 2];
    cpad[i] = make_float4(x, y, z, 0.f);
  }
}

extern "C" void kernel_launch(void* const* d_in, const int* in_sizes, int n_in,
                              void* d_out, int out_size, void* d_ws, size_t ws_size,
                              hipStream_t stream) {
  const float* coords = (const float*)d_in[0];
  const float* Wmat = (const float*)d_in[1];
  float* out = (float*)d_out;

  float4* cpad = (float4*)d_ws;
  u64* part = (u64*)((char*)d_ws + (size_t)NQTOT * sizeof(float4));

  prep_kernel<<<dim3((NQTOT + 255) / 256), dim3(256), 0, stream>>>(coords, cpad);
  knn_kernel<<<dim3(NBATCH, NPTS / QPB, NCHUNK), dim3(TKNN), 0, stream>>>(cpad, part);
  feat_kernel<<<dim3(NQTOT / TFEAT), dim3(TFEAT), 0, stream>>>(cpad, part, Wmat, out);
}